// Round 5
// baseline (224.845 us; speedup 1.0000x reference)
//
#include <hip/hip_runtime.h>
#include <hip/hip_bf16.h>
#include <climits>

#define S 8192
#define D_DIM 128
#define MAXL 16
#define MAXC 1024
#define NB 8
#define ROWS (NB * (S - 1))          // 65528 boundary rows
#define ROWS_PER_BLK 16              // 4 waves x 4 rows

// ---------------------------------------------------------------------------
// Fused kernel A+B: boundary bits + per-batch scan via last-block ticket.
//
// Phase 1 (all 4096 blocks): 4 rows/wave, 16 lanes/row, 8 features/lane,
//   f64 difference-accumulation (sign-exact vs f32 reference), 4 xor-shuffle
//   reduce rounds, 1 byte per row.
// Phase 2 (last finishing block per batch): 256-thread scan of that batch's
//   8192 boundary bytes -> compact first MAXC boundary positions -> prefix-min
//   of g_k = t_k+1-16k -> ends[k] = 16k + min(16, M_k).  Deadlock-free: the
//   last block does the work itself, nobody polls.
// ---------------------------------------------------------------------------
__global__ __launch_bounds__(256) void bnd_scan_kernel(
    const float* __restrict__ x, const float* __restrict__ W,
    const float* __restrict__ bias, unsigned char* __restrict__ bnd,
    int* __restrict__ ends, int* __restrict__ numEv, int* __restrict__ cnt_) {
  int tid = threadIdx.x;
  int lane = tid & 63;
  int wv = tid >> 6;           // wave in block (0..3)
  int sub = lane >> 4;         // row within wave (0..3)
  int fg = lane & 15;          // feature group (8 features each)
  int row = blockIdx.x * ROWS_PER_BLK + wv * 4 + sub;
  bool valid = row < ROWS;
  double d = 0.0;
  int b = 0, t = 0;
  if (valid) {
    b = row / (S - 1);
    t = row - b * (S - 1);
    const float* xr = x + ((size_t)b * S + t) * D_DIM + fg * 8;
    float4 xa = ((const float4*)xr)[0];
    float4 xb = ((const float4*)xr)[1];
    const float* wr = W + fg * 16;     // W (128,2) row-major
    float4 w0 = ((const float4*)wr)[0];
    float4 w1 = ((const float4*)wr)[1];
    float4 w2 = ((const float4*)wr)[2];
    float4 w3 = ((const float4*)wr)[3];
    d += (double)xa.x * ((double)w0.x - (double)w0.y);
    d += (double)xa.y * ((double)w0.z - (double)w0.w);
    d += (double)xa.z * ((double)w1.x - (double)w1.y);
    d += (double)xa.w * ((double)w1.z - (double)w1.w);
    d += (double)xb.x * ((double)w2.x - (double)w2.y);
    d += (double)xb.y * ((double)w2.z - (double)w2.w);
    d += (double)xb.z * ((double)w3.x - (double)w3.y);
    d += (double)xb.w * ((double)w3.z - (double)w3.w);
  }
  for (int m = 1; m < 16; m <<= 1) d += __shfl_xor(d, m, 64);
  if (valid && fg == 0) {
    double thr = (double)bias[1] - (double)bias[0];
    bnd[b * S + t] = (d > thr) ? 1 : 0;
  }

  // ---- ticket: which batches did this block complete? ----
  __shared__ int doscan[2];
  __shared__ int sbatch[2];
  __syncthreads();
  if (tid == 0) {
    __threadfence();                       // release the block's bnd writes
    int r0 = blockIdx.x * ROWS_PER_BLK;
    int r1 = r0 + ROWS_PER_BLK - 1;
    if (r1 > ROWS - 1) r1 = ROWS - 1;
    int b0 = r0 / (S - 1);
    int b1 = r1 / (S - 1);
    doscan[0] = doscan[1] = 0;
    sbatch[0] = b0; sbatch[1] = b1;
    int nb = (b1 > b0) ? 2 : 1;
    for (int k = 0; k < nb; ++k) {
      int bb = (k == 0) ? b0 : b1;
      int first = (bb * (S - 1)) / ROWS_PER_BLK;
      int last = (bb * (S - 1) + S - 2) / ROWS_PER_BLK;
      int tgt = last - first + 1;
      int old = atomicAdd(&cnt_[bb], 1);
      if (old == tgt - 1) doscan[k] = 1;
    }
  }
  __syncthreads();
  if (!(doscan[0] | doscan[1])) return;

  // ---- phase 2: scan (executed by at most one block per batch) ----
  __shared__ int evpos[MAXC];
  __shared__ int wsum[4];
  __shared__ int wmin[4];
  __shared__ int s_total;

  for (int k = 0; k < 2; ++k) {
    if (!doscan[k]) continue;
    if (k == 1 && doscan[0] && sbatch[1] == sbatch[0]) continue;
    int bb = sbatch[k];
    __threadfence();                       // acquire other blocks' bnd writes
    const unsigned long long* p = (const unsigned long long*)(bnd + bb * S);
    unsigned long long w[4];
#pragma unroll
    for (int i = 0; i < 4; ++i) w[i] = p[4 * tid + i];
    if (tid == 255) w[3] &= 0x00FFFFFFFFFFFFFFull;  // no boundary at S-1
    int cnt = 0;
#pragma unroll
    for (int i = 0; i < 4; ++i)
      cnt += __popcll(w[i] & 0x0101010101010101ull);

    // inclusive wave scan (sum)
    int inc = cnt;
    for (int off = 1; off < 64; off <<= 1) {
      int v = __shfl_up(inc, off, 64);
      if (lane >= off) inc += v;
    }
    if (lane == 63) wsum[wv] = inc;
    __syncthreads();
    if (tid == 0) {
      int a = 0;
#pragma unroll
      for (int i = 0; i < 4; ++i) { int v = wsum[i]; wsum[i] = a; a += v; }
      s_total = a;
    }
    __syncthreads();
    int excl = wsum[wv] + inc - cnt;

    // compact boundary positions (each thread owns 32 consecutive bytes)
    int idx = excl;
#pragma unroll
    for (int i = 0; i < 4; ++i) {
      unsigned long long wi = w[i];
      for (int j = 0; j < 8; ++j) {
        if ((wi >> (8 * j)) & 1ull) {
          if (idx < MAXC) evpos[idx] = tid * 32 + i * 8 + j;
          idx++;
        }
      }
    }
    __syncthreads();
    int total = s_total;
    int nev = total < MAXC ? total : MAXC;

    // prefix-min of g_j = evpos[j]+1-16j, 4 events per thread
    int m[4];
    int run = INT_MAX;
#pragma unroll
    for (int i = 0; i < 4; ++i) {
      int j = 4 * tid + i;
      int g = (j < nev) ? (evpos[j] + 1 - MAXL * j) : INT_MAX;
      run = run < g ? run : g;
      m[i] = run;
    }
    int incm = run;
    for (int off = 1; off < 64; off <<= 1) {
      int v = __shfl_up(incm, off, 64);
      if (lane >= off) incm = incm < v ? incm : v;
    }
    if (lane == 63) wmin[wv] = incm;
    __syncthreads();
    if (tid == 0) {
      int a = INT_MAX;
#pragma unroll
      for (int i = 0; i < 4; ++i) { int v = wmin[i]; wmin[i] = a; a = a < v ? a : v; }
    }
    __syncthreads();
    int exm = __shfl_up(incm, 1, 64);
    if (lane == 0) exm = INT_MAX;
    int pre = wmin[wv] < exm ? wmin[wv] : exm;   // exclusive prefix-min
#pragma unroll
    for (int i = 0; i < 4; ++i) {
      int j = 4 * tid + i;
      if (j < nev) {
        int cum = pre < m[i] ? pre : m[i];
        int cap = cum < MAXL ? cum : MAXL;
        ends[bb * MAXC + j] = MAXL * j + cap;
      }
    }
    if (tid == 0) numEv[bb] = nev;
    __syncthreads();   // LDS reuse if this block scans two batches
  }
}

// ---------------------------------------------------------------------------
// Kernel C: output gather.  32 threads (float4 each) per output row (b,c,l).
// ---------------------------------------------------------------------------
__global__ __launch_bounds__(256) void out_kernel(
    const float* __restrict__ x, const float* __restrict__ pad,
    const int* __restrict__ xids, const int* __restrict__ pad_id,
    const int* __restrict__ ends, const int* __restrict__ numEv,
    float* __restrict__ out_t, float* __restrict__ out_ids) {
  int gid = blockIdx.x * 256 + threadIdx.x;
  int row = gid >> 5;   // (b, c, l)
  int q = gid & 31;     // float4 index within the 128-float row
  int b = row >> 14;    // 16384 rows per batch
  int rem = row & 16383;
  int c = rem >> 4;
  int l = rem & 15;
  int nev = numEv[b];
  int tok = -1;
  if (c < nev) {
    int e = ends[b * MAXC + c];
    int s = c ? ends[b * MAXC + c - 1] : 0;
    if (l < e - s) tok = s + l;
  }
  float4 o = ((const float4*)pad)[q];
  if (tok >= 0) {
    float4 xv = ((const float4*)(x + ((size_t)(b * S + tok)) * D_DIM))[q];
    o.x += xv.x; o.y += xv.y; o.z += xv.z; o.w += xv.w;
  }
  ((float4*)out_t)[(size_t)row * 32 + q] = o;
  if (q == 0) {
    out_ids[row] = (tok >= 0) ? (float)xids[b * S + tok] : (float)(*pad_id);
  }
}

extern "C" void kernel_launch(void* const* d_in, const int* in_sizes, int n_in,
                              void* d_out, int out_size, void* d_ws, size_t ws_size,
                              hipStream_t stream) {
  const float* x = (const float*)d_in[0];
  const float* pad_vec = (const float*)d_in[1];
  const int* x_ids = (const int*)d_in[2];
  const int* pad_id = (const int*)d_in[3];
  const float* W = (const float*)d_in[4];
  const float* bias = (const float*)d_in[5];

  unsigned char* bnd = (unsigned char*)d_ws;                       // NB*S bytes
  int* ends = (int*)((char*)d_ws + NB * S);                        // NB*MAXC ints
  int* numEv = (int*)((char*)d_ws + NB * S + NB * MAXC * 4);       // NB ints
  int* cnt_ = (int*)((char*)d_ws + NB * S + NB * MAXC * 4 + NB * 4); // NB ints

  float* out_t = (float*)d_out;                        // NB*MAXC*MAXL*D
  float* out_ids = out_t + (size_t)NB * MAXC * MAXL * D_DIM;

  // zero the ticket counters (ws is poisoned 0xAA before every timed launch)
  hipMemsetAsync(cnt_, 0, NB * sizeof(int), stream);

  // A+B fused: boundary bits + per-batch scan via last-block ticket
  int blocksA = (ROWS + ROWS_PER_BLK - 1) / ROWS_PER_BLK;   // 4096
  hipLaunchKernelGGL(bnd_scan_kernel, dim3(blocksA), dim3(256), 0, stream,
                     x, W, bias, bnd, ends, numEv, cnt_);

  // C: gather + write
  int out_rows = NB * MAXC * MAXL;          // 131072
  int blocksC = out_rows / 8;               // 8 rows per 256-thread block
  hipLaunchKernelGGL(out_kernel, dim3(blocksC), dim3(256), 0, stream,
                     x, pad_vec, x_ids, pad_id, ends, numEv, out_t, out_ids);
}

// Round 6
// 112.435 us; speedup vs baseline: 1.9998x; 1.9998x over previous
//
#include <hip/hip_runtime.h>
#include <hip/hip_bf16.h>
#include <climits>

#define S 8192
#define D_DIM 128
#define MAXL 16
#define MAXC 1024
#define NB 8

// ---------------------------------------------------------------------------
// Kernel A: boundary bits.  4 rows per wave, 16 lanes per row, 8 features
// per lane.  Accumulate the logit DIFFERENCE (col0 - col1) in f64, reduce
// across the 16-lane group with 4 xor-shuffle rounds.
// NOTE (R5 lesson): do NOT fuse the scan in via last-block ticket — per-block
// device-scope __threadfence + same-cacheline atomics serialize across the 8
// non-coherent XCD L2s and cost ~100 µs (measured: VALUBusy 1.7%, HBM 1.3%).
// ---------------------------------------------------------------------------
__global__ __launch_bounds__(256) void bnd_kernel(
    const float* __restrict__ x, const float* __restrict__ W,
    const float* __restrict__ bias, unsigned char* __restrict__ bnd) {
  int gtid = blockIdx.x * 256 + threadIdx.x;
  int wid = gtid >> 6;         // wave id
  int lane = threadIdx.x & 63;
  int sub = lane >> 4;         // row within wave (0..3)
  int fg = lane & 15;          // feature group (8 features each)
  int row = wid * 4 + sub;
  bool valid = row < NB * (S - 1);
  double d = 0.0;
  int b = 0, t = 0;
  if (valid) {
    b = row / (S - 1);
    t = row - b * (S - 1);
    const float* xr = x + ((size_t)b * S + t) * D_DIM + fg * 8;
    float4 xa = ((const float4*)xr)[0];
    float4 xb = ((const float4*)xr)[1];
    // W is (128,2) row-major; features [fg*8, fg*8+8) -> floats [fg*16, fg*16+16)
    const float* wr = W + fg * 16;
    float4 w0 = ((const float4*)wr)[0];
    float4 w1 = ((const float4*)wr)[1];
    float4 w2 = ((const float4*)wr)[2];
    float4 w3 = ((const float4*)wr)[3];
    d += (double)xa.x * ((double)w0.x - (double)w0.y);
    d += (double)xa.y * ((double)w0.z - (double)w0.w);
    d += (double)xa.z * ((double)w1.x - (double)w1.y);
    d += (double)xa.w * ((double)w1.z - (double)w1.w);
    d += (double)xb.x * ((double)w2.x - (double)w2.y);
    d += (double)xb.y * ((double)w2.z - (double)w2.w);
    d += (double)xb.z * ((double)w3.x - (double)w3.y);
    d += (double)xb.w * ((double)w3.z - (double)w3.w);
  }
  // reduce across the 16 lanes of this row group (xor masks 1,2,4,8)
  for (int m = 1; m < 16; m <<= 1) d += __shfl_xor(d, m, 64);
  if (valid && fg == 0) {
    double thr = (double)bias[1] - (double)bias[0];
    bnd[b * S + t] = (d > thr) ? 1 : 0;
  }
}

// ---------------------------------------------------------------------------
// Kernel B: per-batch scan, 1 block (1024 thr = 16 waves) per batch.
// Two-level wave-shuffle scans instead of Hillis-Steele.
//  1. prefix-sum of boundary flags -> compact first MAXC boundary positions
//  2. prefix-min of g_k = t_k + 1 - 16k  ->  ends[k] = 16k + min(16, M_k)
// ---------------------------------------------------------------------------
__global__ __launch_bounds__(1024) void scan_kernel(
    const unsigned char* __restrict__ bnd, int* __restrict__ ends,
    int* __restrict__ numEv) {
  int b = blockIdx.x;
  int tid = threadIdx.x;
  int lane = tid & 63;
  int wv = tid >> 6;           // wave index (0..15)
  __shared__ int wsum[16];
  __shared__ int wmin[16];
  __shared__ int evpos[1024];
  __shared__ int s_total;

  const unsigned char* bb = bnd + b * S;
  unsigned long long w = *(const unsigned long long*)(bb + tid * 8);
  if (tid == 1023) w &= 0x00FFFFFFFFFFFFFFull;  // position S-1 has no boundary
  unsigned long long bits = w & 0x0101010101010101ull;
  int cnt = __popcll(bits);

  // wave-level inclusive sum scan
  int inc = cnt;
  for (int off = 1; off < 64; off <<= 1) {
    int v = __shfl_up(inc, off, 64);
    if (lane >= off) inc += v;
  }
  if (lane == 63) wsum[wv] = inc;
  __syncthreads();
  if (wv == 0 && lane < 16) {
    int v = wsum[lane];
    int iv = v;
    for (int off = 1; off < 16; off <<= 1) {
      int u = __shfl_up(iv, off, 64);
      if (lane >= off) iv += u;
    }
    if (lane == 15) s_total = iv;
    wsum[lane] = iv - v;       // exclusive wave offset
  }
  __syncthreads();
  int excl = wsum[wv] + inc - cnt;  // exclusive prefix over whole block

  // compact boundary positions
  int idx = excl;
#pragma unroll
  for (int i = 0; i < 8; ++i) {
    if ((w >> (8 * i)) & 1ull) {
      if (idx < MAXC) evpos[idx] = tid * 8 + i;
      idx++;
    }
  }
  __syncthreads();
  int total = s_total;
  int nev = total < MAXC ? total : MAXC;

  // prefix-min of g
  int g = (tid < nev) ? (evpos[tid] + 1 - MAXL * tid) : INT_MAX;
  int incm = g;
  for (int off = 1; off < 64; off <<= 1) {
    int v = __shfl_up(incm, off, 64);
    if (lane >= off) incm = incm < v ? incm : v;
  }
  if (lane == 63) wmin[wv] = incm;
  __syncthreads();
  if (wv == 0 && lane < 16) {
    int iv = wmin[lane];
    for (int off = 1; off < 16; off <<= 1) {
      int u = __shfl_up(iv, off, 64);
      if (lane >= off) iv = iv < u ? iv : u;
    }
    int ex = __shfl_up(iv, 1, 64);   // exclusive: min over preceding waves
    if (lane == 0) ex = INT_MAX;
    wmin[lane] = ex;
  }
  __syncthreads();
  int wex = wmin[wv];
  int m = incm < wex ? incm : wex;

  if (tid < nev) {
    int cap = m < MAXL ? m : MAXL;
    ends[b * MAXC + tid] = MAXL * tid + cap;
  }
  if (tid == 0) numEv[b] = nev;
}

// ---------------------------------------------------------------------------
// Kernel C: output gather.  32 threads (float4 each) per output row (b,c,l).
// ---------------------------------------------------------------------------
__global__ __launch_bounds__(256) void out_kernel(
    const float* __restrict__ x, const float* __restrict__ pad,
    const int* __restrict__ xids, const int* __restrict__ pad_id,
    const int* __restrict__ ends, const int* __restrict__ numEv,
    float* __restrict__ out_t, float* __restrict__ out_ids) {
  int gid = blockIdx.x * 256 + threadIdx.x;
  int row = gid >> 5;   // (b, c, l)
  int q = gid & 31;     // float4 index within the 128-float row
  int b = row >> 14;    // 16384 rows per batch
  int rem = row & 16383;
  int c = rem >> 4;
  int l = rem & 15;
  int nev = numEv[b];
  int tok = -1;
  if (c < nev) {
    int e = ends[b * MAXC + c];
    int s = c ? ends[b * MAXC + c - 1] : 0;
    if (l < e - s) tok = s + l;
  }
  float4 o = ((const float4*)pad)[q];
  if (tok >= 0) {
    float4 xv = ((const float4*)(x + ((size_t)(b * S + tok)) * D_DIM))[q];
    o.x += xv.x; o.y += xv.y; o.z += xv.z; o.w += xv.w;
  }
  ((float4*)out_t)[(size_t)row * 32 + q] = o;
  if (q == 0) {
    out_ids[row] = (tok >= 0) ? (float)xids[b * S + tok] : (float)(*pad_id);
  }
}

extern "C" void kernel_launch(void* const* d_in, const int* in_sizes, int n_in,
                              void* d_out, int out_size, void* d_ws, size_t ws_size,
                              hipStream_t stream) {
  const float* x = (const float*)d_in[0];
  const float* pad_vec = (const float*)d_in[1];
  const int* x_ids = (const int*)d_in[2];
  const int* pad_id = (const int*)d_in[3];
  const float* W = (const float*)d_in[4];
  const float* bias = (const float*)d_in[5];

  unsigned char* bnd = (unsigned char*)d_ws;                 // NB*S bytes
  int* ends = (int*)((char*)d_ws + NB * S);                  // NB*MAXC ints
  int* numEv = (int*)((char*)d_ws + NB * S + NB * MAXC * 4); // NB ints

  float* out_t = (float*)d_out;                       // NB*MAXC*MAXL*D
  float* out_ids = out_t + (size_t)NB * MAXC * MAXL * D_DIM;

  // A: boundary bits — 4 rows per wave
  int rows = NB * (S - 1);
  int waves = (rows + 3) / 4;
  int blocksA = (waves * 64 + 255) / 256;
  hipLaunchKernelGGL(bnd_kernel, dim3(blocksA), dim3(256), 0, stream,
                     x, W, bias, bnd);

  // B: per-batch scan
  hipLaunchKernelGGL(scan_kernel, dim3(NB), dim3(1024), 0, stream,
                     bnd, ends, numEv);

  // C: gather + write
  int out_rows = NB * MAXC * MAXL;          // 131072
  int blocksC = out_rows / 8;               // 8 rows per 256-thread block
  hipLaunchKernelGGL(out_kernel, dim3(blocksC), dim3(256), 0, stream,
                     x, pad_vec, x_ids, pad_id, ends, numEv, out_t, out_ids);
}